// Round 1
// 407.537 us; speedup vs baseline: 1.0669x; 1.0669x over previous
//
#include <hip/hip_runtime.h>

#define HW 3136
#define C_ 256
#define T_ 8
#define NPOS 64
#define NBLK_PER_NT 49  // 3136/64
#define YSTRIDE 40      // ushorts per LDS row (32 used + 8 pad) = 80B
#define KP 352          // total nonzero taps = gathered K dimension (11*32)
#define NKS 11          // K-chunks of 32
#define FLAGBIT 0x40000000

typedef __attribute__((ext_vector_type(8))) short bf16x8;
typedef __attribute__((ext_vector_type(4))) float f32x4;
typedef __attribute__((ext_vector_type(4))) unsigned int u32x4;
typedef __attribute__((ext_vector_type(4))) int i32x4;

__device__ __forceinline__ unsigned short f2bf(float f) {
  unsigned int u = __float_as_uint(f);
  u += 0x7FFF + ((u >> 16) & 1);  // round-to-nearest-even
  return (unsigned short)(u >> 16);
}

// ws layout:
// [0,      180224): Wbp bf16 [256 oc][352 slots]   (Net[oc,c] * w_tap, folded)
// [180224, 181632): slotC  int[352]   (channel of each slot)
// [181632, 183040): slotW  float[352] (tap weight of each slot)
// [183040, 194304): rowtab int[8][352] (per-t x row element-offset | FLAGBIT if pad)

// ---- prep 1: extract taps, prefix-sum into slot list, build per-t row tables ----
__global__ void prep_table(const float* __restrict__ w1, const float* __restrict__ w3,
                           const float* __restrict__ w5, const float* __restrict__ w7,
                           int* __restrict__ slotC, float* __restrict__ slotW,
                           int* __restrict__ rowtab) {
  const int c = threadIdx.x;  // one block, 256 threads
  // safety pre-fill (weight 0 => contributes nothing)
  for (int s = c; s < KP; s += 256) {
    slotC[s] = 0;
    slotW[s] = 0.f;
    for (int t = 0; t < T_; ++t) rowtab[t * KP + s] = 0;
  }
  const int g = c >> 6, lc = c & 63, K = 2 * g + 1;
  const float* wsrc = (g == 0) ? w1 : (g == 1) ? w3 : (g == 2) ? w5 : w7;
  float w[3] = {0.f, 0.f, 0.f};
  int d[3] = {0, 0, 0};
  int cnt = 0;
  for (int k = 0; k < K && cnt < 3; ++k) {
    float v = wsrc[lc * K + k];
    if (v != 0.0f) { w[cnt] = v; d[cnt] = k - g; ++cnt; }
  }
  __shared__ int ps[256];
  ps[c] = cnt;
  __syncthreads();
  for (int dlt = 1; dlt < 256; dlt <<= 1) {  // inclusive scan (Hillis-Steele)
    int v = (c >= dlt) ? ps[c - dlt] : 0;
    __syncthreads();
    ps[c] += v;
    __syncthreads();
  }
  const int off = ps[c] - cnt;
  for (int i = 0; i < cnt; ++i) {
    const int s = off + i;
    if (s >= KP) break;
    slotC[s] = c;
    slotW[s] = w[i];
    for (int t = 0; t < T_; ++t) {
      const int tq = t + d[i];
      const bool valid = (unsigned)tq < (unsigned)T_;
      const int tqc = valid ? tq : (tq < 0 ? 0 : T_ - 1);
      rowtab[t * KP + s] = ((tqc * C_ + c) * HW) | (valid ? 0 : FLAGBIT);
    }
  }
}

// ---- prep 2: Wbp[oc][s] = bf16(net_w[oc, slotC[s]] * slotW[s]) ----
__global__ void prep_wb(const float* __restrict__ net_w, const int* __restrict__ slotC,
                        const float* __restrict__ slotW, unsigned short* __restrict__ Wbp) {
  const int oc = blockIdx.x;
  const int s = threadIdx.x;
  if (s < KP) Wbp[oc * KP + s] = f2bf(net_w[oc * C_ + slotC[s]] * slotW[s]);
}

// Block: one (n,t) pair x 64 contiguous spatial positions, all 256 output chans.
// K=352 gathered-x GEMM: 11 chunks of 32 rows. 4 waves; wave w owns oc [w*64, w*64+64).
__global__ __launch_bounds__(256, 4) void fused_kernel(
    const float* __restrict__ x, const unsigned short* __restrict__ Wbp,
    const int* __restrict__ rowtab, float* __restrict__ out) {
  const int blk = blockIdx.x;
  const int nt = blk / NBLK_PER_NT;
  const int p0 = (blk % NBLK_PER_NT) * NPOS;
  const int n = nt >> 3, t = nt & 7;
  const int tid = threadIdx.x;
  const int lane = tid & 63;
  const int wv = tid >> 6;
  const int m16 = lane & 15;
  const int quad = lane >> 4;
  const int pp = tid & 63;     // producer: position within tile (coalesced x loads)
  const int chunk = tid >> 6;  // producer: 8-row chunk (wave-uniform)

  __shared__ __align__(16) unsigned short ylds[2][NPOS * YSTRIDE];  // 10 KiB
  __shared__ __align__(16) int ltab[KP];                            // 1.4 KiB

  // stage this t's row table
  for (int i = tid; i < KP; i += 256) ltab[i] = rowtab[t * KP + i];

  f32x4 acc[4][4];
#pragma unroll
  for (int i = 0; i < 4; ++i)
#pragma unroll
    for (int j = 0; j < 4; ++j) acc[i][j] = (f32x4){0.f, 0.f, 0.f, 0.f};

  const float* xn = x + (size_t)(n * 8) * C_ * HW + (size_t)(p0 + pp);

  __syncthreads();  // ltab ready

  // prologue: load gathered rows for ks=0 (8 wave-uniform rows, lane = position)
  float xv[2][8];
  {
    const i32x4 o0 = *(const i32x4*)&ltab[chunk * 8];
    const i32x4 o1 = *(const i32x4*)&ltab[chunk * 8 + 4];
#pragma unroll
    for (int j = 0; j < 4; ++j) {
      const int ofa = o0[j];
      const float va = xn[ofa & (FLAGBIT - 1)];
      xv[0][j] = (ofa & FLAGBIT) ? 0.f : va;
      const int ofb = o1[j];
      const float vb = xn[ofb & (FLAGBIT - 1)];
      xv[0][4 + j] = (ofb & FLAGBIT) ? 0.f : vb;
    }
  }

#pragma unroll
  for (int ks = 0; ks < NKS; ++ks) {
    const int buf = ks & 1;
    // A-fragments for this chunk: issue early (L2-resident Wbp)
    bf16x8 af[4];
#pragma unroll
    for (int mi = 0; mi < 4; ++mi)
      af[mi] = *(const bf16x8*)&Wbp[(size_t)((wv * 64 + mi * 16 + m16) * KP) + ks * 32 + quad * 8];
    // pack current x rows -> bf16 LDS tile [pos][k]
    unsigned short pk[8];
#pragma unroll
    for (int j = 0; j < 8; ++j) pk[j] = f2bf(xv[buf][j]);
    *(u32x4*)&ylds[buf][pp * YSTRIDE + chunk * 8] = *(const u32x4*)pk;
    // prefetch next chunk's x rows (hidden under barrier + MFMA phase)
    if (ks + 1 < NKS) {
      const i32x4 o0 = *(const i32x4*)&ltab[(ks + 1) * 32 + chunk * 8];
      const i32x4 o1 = *(const i32x4*)&ltab[(ks + 1) * 32 + chunk * 8 + 4];
#pragma unroll
      for (int j = 0; j < 4; ++j) {
        const int ofa = o0[j];
        const float va = xn[ofa & (FLAGBIT - 1)];
        xv[buf ^ 1][j] = (ofa & FLAGBIT) ? 0.f : va;
        const int ofb = o1[j];
        const float vb = xn[ofb & (FLAGBIT - 1)];
        xv[buf ^ 1][4 + j] = (ofb & FLAGBIT) ? 0.f : vb;
      }
    }
    __syncthreads();
    // MFMA phase (double buffer => single barrier per step is safe: the next
    // write of this buf happens only after the NEXT barrier)
#pragma unroll
    for (int ni = 0; ni < 4; ++ni) {
      const bf16x8 bfrag = *(const bf16x8*)&ylds[buf][(ni * 16 + m16) * YSTRIDE + quad * 8];
#pragma unroll
      for (int mi = 0; mi < 4; ++mi)
        acc[mi][ni] =
            __builtin_amdgcn_mfma_f32_16x16x32_bf16(af[mi], bfrag, acc[mi][ni], 0, 0, 0);
    }
  }

  // ---- epilogue: D row(oc) = quad*4 + reg, col(pos) = m16 ----
  const size_t obase = (size_t)nt * C_ * HW + p0 + m16;
#pragma unroll
  for (int mi = 0; mi < 4; ++mi) {
#pragma unroll
    for (int r = 0; r < 4; ++r) {
      const int oc = wv * 64 + mi * 16 + quad * 4 + r;
      float* orow = out + obase + (size_t)oc * HW;
#pragma unroll
      for (int ni = 0; ni < 4; ++ni) orow[ni * 16] = acc[mi][ni][r];
    }
  }
}

extern "C" void kernel_launch(void* const* d_in, const int* in_sizes, int n_in,
                              void* d_out, int out_size, void* d_ws, size_t ws_size,
                              hipStream_t stream) {
  const float* x = (const float*)d_in[0];
  const float* w1 = (const float*)d_in[1];
  const float* w3 = (const float*)d_in[2];
  const float* w5 = (const float*)d_in[3];
  const float* w7 = (const float*)d_in[4];
  const float* net_w = (const float*)d_in[5];
  float* out = (float*)d_out;

  char* ws = (char*)d_ws;
  unsigned short* Wbp = (unsigned short*)ws;
  int* slotC = (int*)(ws + 180224);
  float* slotW = (float*)(ws + 181632);
  int* rowtab = (int*)(ws + 183040);

  hipLaunchKernelGGL(prep_table, dim3(1), dim3(256), 0, stream, w1, w3, w5, w7,
                     slotC, slotW, rowtab);
  hipLaunchKernelGGL(prep_wb, dim3(C_), dim3(384), 0, stream, net_w, slotC, slotW, Wbp);
  hipLaunchKernelGGL(fused_kernel, dim3(64 * NBLK_PER_NT), dim3(256), 0, stream,
                     x, Wbp, rowtab, out);
}

// Round 2
// 396.449 us; speedup vs baseline: 1.0968x; 1.0280x over previous
//
#include <hip/hip_runtime.h>

#define HW 3136
#define C_ 256
#define T_ 8
#define NPOS 64
#define NBLK_PER_NT 49  // 3136/64
#define YSTRIDE 40      // ushorts per LDS row (32 used + 8 pad) = 80B
#define KP 352          // total nonzero taps = gathered K dimension (11*32)
#define NKS 11          // K-chunks of 32
#define FLAGBIT 0x40000000

typedef __attribute__((ext_vector_type(8))) short bf16x8;
typedef __attribute__((ext_vector_type(4))) float f32x4;
typedef __attribute__((ext_vector_type(4))) unsigned int u32x4;
typedef __attribute__((ext_vector_type(4))) int i32x4;

__device__ __forceinline__ unsigned short f2bf(float f) {
  unsigned int u = __float_as_uint(f);
  u += 0x7FFF + ((u >> 16) & 1);  // round-to-nearest-even
  return (unsigned short)(u >> 16);
}

// ws layout:
// [0,      180224): Wbp bf16 [256 oc][352 slots]   (Net[oc,c] * w_tap, folded)
// [180224, 181632): slotC  int[352]   (channel of each slot)
// [181632, 183040): slotW  float[352] (tap weight of each slot)
// [183040, 194304): rowtab int[8][352] (per-t x row element-offset | FLAGBIT if pad)

// ---- prep 1: extract taps, prefix-sum into slot list, build per-t row tables ----
__global__ void prep_table(const float* __restrict__ w1, const float* __restrict__ w3,
                           const float* __restrict__ w5, const float* __restrict__ w7,
                           int* __restrict__ slotC, float* __restrict__ slotW,
                           int* __restrict__ rowtab) {
  const int c = threadIdx.x;  // one block, 256 threads
  for (int s = c; s < KP; s += 256) {
    slotC[s] = 0;
    slotW[s] = 0.f;
    for (int t = 0; t < T_; ++t) rowtab[t * KP + s] = 0;
  }
  const int g = c >> 6, lc = c & 63, K = 2 * g + 1;
  const float* wsrc = (g == 0) ? w1 : (g == 1) ? w3 : (g == 2) ? w5 : w7;
  float w[3] = {0.f, 0.f, 0.f};
  int d[3] = {0, 0, 0};
  int cnt = 0;
  for (int k = 0; k < K && cnt < 3; ++k) {
    float v = wsrc[lc * K + k];
    if (v != 0.0f) { w[cnt] = v; d[cnt] = k - g; ++cnt; }
  }
  __shared__ int ps[256];
  ps[c] = cnt;
  __syncthreads();
  for (int dlt = 1; dlt < 256; dlt <<= 1) {  // inclusive scan (Hillis-Steele)
    int v = (c >= dlt) ? ps[c - dlt] : 0;
    __syncthreads();
    ps[c] += v;
    __syncthreads();
  }
  const int off = ps[c] - cnt;
  for (int i = 0; i < cnt; ++i) {
    const int s = off + i;
    if (s >= KP) break;
    slotC[s] = c;
    slotW[s] = w[i];
    for (int t = 0; t < T_; ++t) {
      const int tq = t + d[i];
      const bool valid = (unsigned)tq < (unsigned)T_;
      const int tqc = valid ? tq : (tq < 0 ? 0 : T_ - 1);
      rowtab[t * KP + s] = ((tqc * C_ + c) * HW) | (valid ? 0 : FLAGBIT);
    }
  }
}

// ---- prep 2: Wbp[oc][s] = bf16(net_w[oc, slotC[s]] * slotW[s]) ----
__global__ void prep_wb(const float* __restrict__ net_w, const int* __restrict__ slotC,
                        const float* __restrict__ slotW, unsigned short* __restrict__ Wbp) {
  const int oc = blockIdx.x;
  const int s = threadIdx.x;
  if (s < KP) Wbp[oc * KP + s] = f2bf(net_w[oc * C_ + slotC[s]] * slotW[s]);
}

// Block: one (n,t) pair x 64 contiguous spatial positions, all 256 output chans.
// K=352 gathered-x GEMM: 11 chunks of 32 rows. 4 waves; wave w owns oc [w*64, w*64+64).
// Raw barriers (lgkmcnt-only) so prefetched x loads stay in flight across steps.
__global__ __launch_bounds__(256, 3) void fused_kernel(
    const float* __restrict__ x, const unsigned short* __restrict__ Wbp,
    const int* __restrict__ rowtab, float* __restrict__ out) {
  const int blk = blockIdx.x;
  const int nt = blk / NBLK_PER_NT;
  const int p0 = (blk % NBLK_PER_NT) * NPOS;
  const int n = nt >> 3, t = nt & 7;
  const int tid = threadIdx.x;
  const int lane = tid & 63;
  const int wv = tid >> 6;
  const int m16 = lane & 15;
  const int quad = lane >> 4;
  const int pp = tid & 63;     // producer: position within tile (coalesced x loads)
  const int chunk = tid >> 6;  // producer: 8-row chunk (wave-uniform)

  __shared__ __align__(16) unsigned short ylds[2][NPOS * YSTRIDE];  // 10 KiB
  __shared__ __align__(16) int ltab[KP];                            // 1.4 KiB

  // stage this t's row table
  for (int i = tid; i < KP; i += 256) ltab[i] = rowtab[t * KP + i];

  f32x4 acc[4][4];
#pragma unroll
  for (int i = 0; i < 4; ++i)
#pragma unroll
    for (int j = 0; j < 4; ++j) acc[i][j] = (f32x4){0.f, 0.f, 0.f, 0.f};

  const float* xn = x + (size_t)(n * 8) * C_ * HW + (size_t)(p0 + pp);

  __syncthreads();  // ltab ready (one full barrier; prologue loads need ltab anyway)

// gathered-row load of chunk KS into DST[8] (8 wave-uniform rows, lane = position)
#define LOADX(KS, DST)                                          \
  do {                                                          \
    const i32x4 o0 = *(const i32x4*)&ltab[(KS) * 32 + chunk * 8];      \
    const i32x4 o1 = *(const i32x4*)&ltab[(KS) * 32 + chunk * 8 + 4];  \
    _Pragma("unroll") for (int j = 0; j < 4; ++j) {             \
      const int ofa = o0[j];                                    \
      const float va = xn[ofa & (FLAGBIT - 1)];                 \
      (DST)[j] = (ofa & FLAGBIT) ? 0.f : va;                    \
      const int ofb = o1[j];                                    \
      const float vb = xn[ofb & (FLAGBIT - 1)];                 \
      (DST)[4 + j] = (ofb & FLAGBIT) ? 0.f : vb;                \
    }                                                           \
  } while (0)

  // prologue: prefetch depth 2
  float xv[3][8];
  LOADX(0, xv[0]);
  LOADX(1, xv[1]);

#pragma unroll
  for (int ks = 0; ks < NKS; ++ks) {
    const int cur = ks % 3;
    const int nxt = (ks + 2) % 3;
    const int buf = ks & 1;
    // A-fragments for this chunk (L2-resident Wbp), issued ahead of the barrier
    bf16x8 af[4];
#pragma unroll
    for (int mi = 0; mi < 4; ++mi)
      af[mi] = *(const bf16x8*)&Wbp[(size_t)((wv * 64 + mi * 16 + m16) * KP) + ks * 32 + quad * 8];
    // pack current x rows -> bf16 LDS tile [pos][k]
    unsigned short pk[8];
#pragma unroll
    for (int j = 0; j < 8; ++j) pk[j] = f2bf(xv[cur][j]);
    *(u32x4*)&ylds[buf][pp * YSTRIDE + chunk * 8] = *(const u32x4*)pk;
    // prefetch chunk ks+2 (stays in flight across the raw barrier below)
    if (ks + 2 < NKS) LOADX(ks + 2, xv[nxt]);
    // raw barrier: drain LDS only — NO vmcnt drain (this is the whole point)
    __builtin_amdgcn_sched_barrier(0);
    asm volatile("s_waitcnt lgkmcnt(0)" ::: "memory");
    __builtin_amdgcn_s_barrier();
    __builtin_amdgcn_sched_barrier(0);
    // MFMA phase (double buffer => single barrier per step is safe: the next
    // write of this buf happens only after the NEXT barrier)
#pragma unroll
    for (int ni = 0; ni < 4; ++ni) {
      const bf16x8 bfrag = *(const bf16x8*)&ylds[buf][(ni * 16 + m16) * YSTRIDE + quad * 8];
#pragma unroll
      for (int mi = 0; mi < 4; ++mi)
        acc[mi][ni] =
            __builtin_amdgcn_mfma_f32_16x16x32_bf16(af[mi], bfrag, acc[mi][ni], 0, 0, 0);
    }
  }
#undef LOADX

  // ---- epilogue: D row(oc) = quad*4 + reg, col(pos) = m16 ----
  const size_t obase = (size_t)nt * C_ * HW + p0 + m16;
#pragma unroll
  for (int mi = 0; mi < 4; ++mi) {
#pragma unroll
    for (int r = 0; r < 4; ++r) {
      const int oc = wv * 64 + mi * 16 + quad * 4 + r;
      float* orow = out + obase + (size_t)oc * HW;
#pragma unroll
      for (int ni = 0; ni < 4; ++ni) orow[ni * 16] = acc[mi][ni][r];
    }
  }
}

extern "C" void kernel_launch(void* const* d_in, const int* in_sizes, int n_in,
                              void* d_out, int out_size, void* d_ws, size_t ws_size,
                              hipStream_t stream) {
  const float* x = (const float*)d_in[0];
  const float* w1 = (const float*)d_in[1];
  const float* w3 = (const float*)d_in[2];
  const float* w5 = (const float*)d_in[3];
  const float* w7 = (const float*)d_in[4];
  const float* net_w = (const float*)d_in[5];
  float* out = (float*)d_out;

  char* ws = (char*)d_ws;
  unsigned short* Wbp = (unsigned short*)ws;
  int* slotC = (int*)(ws + 180224);
  float* slotW = (float*)(ws + 181632);
  int* rowtab = (int*)(ws + 183040);

  hipLaunchKernelGGL(prep_table, dim3(1), dim3(256), 0, stream, w1, w3, w5, w7,
                     slotC, slotW, rowtab);
  hipLaunchKernelGGL(prep_wb, dim3(C_), dim3(384), 0, stream, net_w, slotC, slotW, Wbp);
  hipLaunchKernelGGL(fused_kernel, dim3(64 * NBLK_PER_NT), dim3(256), 0, stream,
                     x, Wbp, rowtab, out);
}